// Round 1
// baseline (93.286 us; speedup 1.0000x reference)
//
#include <hip/hip_runtime.h>
#include <hip/hip_bf16.h>
#include <math.h>

// Problem constants (from reference file: B=8, L_IN=4096, D=256, T_OUT=1024)
#define BB   8
#define LL   4096
#define DD   256
#define TT   1024
#define EPSV 1e-12f

// ---------------------------------------------------------------------------
// Kernel 1: per-batch valid length = sum(mask[b, :]).
// Handles BOTH plausible device layouts of the bool mask:
//   - int32 (harness "integer -> const int*" convention): first elem == 1
//   - uint8 (raw numpy bool bytes): first 4 bytes are 1,1,1,1 -> 0x01010101
// mask[0][0] is always true here (lengths >= L/2), so the probe is safe.
// ---------------------------------------------------------------------------
__global__ __launch_bounds__(64) void lengths_kernel(const void* __restrict__ mask,
                                                     int* __restrict__ lengths) {
    const int b    = blockIdx.x;
    const int lane = threadIdx.x;  // 64 threads = 1 wave
    const int* mi32 = (const int*)mask;
    const bool is_i32 = (mi32[0] == 1);

    int sum = 0;
    if (is_i32) {
        const int* p = mi32 + (size_t)b * LL;
        for (int i = lane; i < LL; i += 64) sum += (p[i] != 0);
    } else {
        const unsigned char* p = (const unsigned char*)mask + (size_t)b * LL;
        for (int i = lane; i < LL; i += 64) sum += (p[i] != 0);
    }
    // wave-64 butterfly reduce
    for (int off = 32; off > 0; off >>= 1) sum += __shfl_down(sum, off, 64);
    if (lane == 0) lengths[b] = sum;
}

// ---------------------------------------------------------------------------
// Kernel 2: fused area-pool (mean) + fractional-overlap weighted std.
// One block per (b, t) output bin; thread d handles channel d (coalesced row
// loads, 1 KB per row per block). The A-support and W-support row ranges are
// identical: [floor(t*step), ceil((t+1)*step)) with step = Lb/T in [2,4].
// All index math (t*Lb/1024 etc.) is exact in f32 (t*Lb < 2^22), matching the
// reference bit-for-bit on weights; Wsum == step exactly.
// ---------------------------------------------------------------------------
__global__ __launch_bounds__(256) void changelen_kernel(const float* __restrict__ x,
                                                        const int* __restrict__ lengths,
                                                        float* __restrict__ out) {
    const int bt = blockIdx.x;       // 0 .. B*T-1
    const int b  = bt >> 10;         // / TT
    const int t  = bt & (TT - 1);    // % TT
    const int d  = threadIdx.x;

    const float Lb    = (float)lengths[b];
    const float step  = Lb * (1.0f / (float)TT);        // exact (Lb < 2^13, /2^10)
    const float start = (float)t * step;                // exact (t*Lb < 2^22)
    const float end   = start + step;                   // exact (multiples of 2^-10)
    const float s_f   = floorf(start);
    const float e_f   = ceilf(end);
    const int   s     = (int)s_f;
    const int   e     = (int)e_f;                       // e <= Lb (end <= Lb)
    const float inv_cnt = 1.0f / fmaxf(e_f - s_f, 1.0f);

    float sumA = 0.0f, sw = 0.0f, sw2 = 0.0f;
    const float* xp = x + ((size_t)b * LL + (size_t)s) * DD + d;
    for (int i = s; i < e; ++i) {
        const float v = *xp;
        xp += DD;
        float w = fminf((float)(i + 1), end) - fmaxf((float)i, start);
        w = fmaxf(w, 0.0f);
        sumA += v;
        sw  = fmaf(w, v, sw);
        sw2 = fmaf(w, v * v, sw2);
    }

    const float mean = sw / step;     // Wsum == step exactly
    const float msq  = sw2 / step;
    const float var  = fmaxf(msq - mean * mean, EPSV);
    const float stdv = sqrtf(var);

    const size_t o_pool = ((size_t)b * TT + (size_t)t) * DD + (size_t)d;
    const size_t base_std = (size_t)BB * TT * DD + (size_t)BB * TT;
    out[o_pool] = sumA * inv_cnt;                 // padded_out (output 0)
    out[base_std + o_pool] = stdv;                // std_out    (output 2)
    if (d == 0) {
        out[(size_t)BB * TT * DD + (size_t)bt] = 1.0f;  // out_mask (output 1)
    }
}

extern "C" void kernel_launch(void* const* d_in, const int* in_sizes, int n_in,
                              void* d_out, int out_size, void* d_ws, size_t ws_size,
                              hipStream_t stream) {
    const float* x    = (const float*)d_in[0];
    const void*  mask = d_in[1];
    // d_in[2] = finallength (always 1024, hard-coded as TT)
    float* out     = (float*)d_out;
    int*   lengths = (int*)d_ws;   // 8 ints of scratch

    lengths_kernel<<<BB, 64, 0, stream>>>(mask, lengths);
    changelen_kernel<<<BB * TT, DD, 0, stream>>>(x, lengths, out);
}

// Round 2
// 82.594 us; speedup vs baseline: 1.1295x; 1.1295x over previous
//
#include <hip/hip_runtime.h>
#include <hip/hip_bf16.h>
#include <math.h>

// Problem constants (from reference file: B=8, L_IN=4096, D=256, T_OUT=1024)
#define BB   8
#define LL   4096
#define DD   256
#define TT   1024
#define EPSV 1e-12f

// ---------------------------------------------------------------------------
// Single fused kernel. One WAVE per (b,t) output bin; 4 bins per 256-thread
// block. Each lane handles 4 channels via float4 (16 B/lane coalescing sweet
// spot: one row = 64 lanes x 16 B = 1 KB contiguous).
//
// Lb (valid length) is recovered per-wave by a 64-ary search on the prefix
// mask: 2 dependent L2-hit loads + ballot/popcount — cheap enough to do
// redundantly in every wave, which removes the separate lengths kernel and
// its serializing dependency (Round-1's 93 us was dominated by an 8-wave
// latency-bound reduction kernel gating the main kernel).
//
// The area-pool support [floor(t*step), ceil((t+1)*step)) and the fractional
// W support are the same row range (step = Lb/1024 in [2,4], <=5 rows).
// All weight math is exact in f32 (t*Lb < 2^22); Wsum == step exactly.
// ---------------------------------------------------------------------------
__global__ __launch_bounds__(256) void changelen_fused(const float* __restrict__ x,
                                                       const void* __restrict__ mask,
                                                       float* __restrict__ out) {
    const int wave = threadIdx.x >> 6;
    const int lane = threadIdx.x & 63;
    const int bt   = (blockIdx.x << 2) + wave;   // 0 .. B*T-1
    const int b    = bt >> 10;                   // / TT
    const int t    = bt & (TT - 1);              // % TT

    // ---- 64-ary prefix-mask search for Lb ----
    const int* mi32 = (const int*)mask;
    const unsigned char* mu8 = (const unsigned char*)mask;
    const bool is_i32 = (mi32[0] == 1);          // layout probe (mask[0][0] is true)

    bool p1;
    if (is_i32) p1 = (mi32[(size_t)b * LL + lane * 64 + 63] != 0);
    else        p1 = (mu8 [(size_t)b * LL + lane * 64 + 63] != 0);
    const int n1 = __popcll(__ballot(p1));       // floor(Lb/64)
    int Lbi;
    if (n1 == 64) {
        Lbi = LL;                                // all-true row; avoid OOB probe
    } else {
        const int base = n1 << 6;
        bool p2;
        if (is_i32) p2 = (mi32[(size_t)b * LL + base + lane] != 0);
        else        p2 = (mu8 [(size_t)b * LL + base + lane] != 0);
        Lbi = base + __popcll(__ballot(p2));
    }

    // ---- bin geometry (exact in f32) ----
    const float Lb    = (float)Lbi;
    const float step  = Lb * (1.0f / (float)TT);
    const float start = (float)t * step;
    const float end   = start + step;
    const float s_f   = floorf(start);
    const float e_f   = ceilf(end);
    const int   s     = (int)s_f;
    const int   e     = (int)e_f;                // e <= Lbi <= LL
    const float inv_cnt = 1.0f / fmaxf(e_f - s_f, 1.0f);

    // ---- accumulate over <=5 rows, float4 per lane ----
    float4 sumA = {0.f, 0.f, 0.f, 0.f};
    float4 sw   = {0.f, 0.f, 0.f, 0.f};
    float4 sw2  = {0.f, 0.f, 0.f, 0.f};
    const float4* xp = (const float4*)(x + ((size_t)b * LL + (size_t)s) * DD) + lane;
    for (int i = s; i < e; ++i) {
        const float4 v = *xp;
        xp += DD / 4;
        float w = fminf((float)(i + 1), end) - fmaxf((float)i, start);
        w = fmaxf(w, 0.0f);
        sumA.x += v.x; sumA.y += v.y; sumA.z += v.z; sumA.w += v.w;
        sw.x = fmaf(w, v.x, sw.x); sw.y = fmaf(w, v.y, sw.y);
        sw.z = fmaf(w, v.z, sw.z); sw.w = fmaf(w, v.w, sw.w);
        sw2.x = fmaf(w, v.x * v.x, sw2.x); sw2.y = fmaf(w, v.y * v.y, sw2.y);
        sw2.z = fmaf(w, v.z * v.z, sw2.z); sw2.w = fmaf(w, v.w * v.w, sw2.w);
    }

    // ---- epilogue: mean-pool, std; vector stores ----
    float4 pool, stdv;
    {
        pool.x = sumA.x * inv_cnt; pool.y = sumA.y * inv_cnt;
        pool.z = sumA.z * inv_cnt; pool.w = sumA.w * inv_cnt;
        const float mx = sw.x / step, my = sw.y / step, mz = sw.z / step, mw = sw.w / step;
        const float qx = sw2.x / step, qy = sw2.y / step, qz = sw2.z / step, qw = sw2.w / step;
        stdv.x = sqrtf(fmaxf(qx - mx * mx, EPSV));
        stdv.y = sqrtf(fmaxf(qy - my * my, EPSV));
        stdv.z = sqrtf(fmaxf(qz - mz * mz, EPSV));
        stdv.w = sqrtf(fmaxf(qw - mw * mw, EPSV));
    }

    float4* out4 = (float4*)out;
    const size_t o_pool4 = (size_t)bt * (DD / 4) + (size_t)lane;       // padded_out
    // std_out starts after padded_out (B*T*D floats) + out_mask (B*T floats);
    // byte offset (2,105,344 floats) is 16B-aligned.
    const size_t std_base4 = ((size_t)BB * TT * DD + (size_t)BB * TT) / 4;
    out4[o_pool4] = pool;
    out4[std_base4 + o_pool4] = stdv;
    if (lane == 0) {
        out[(size_t)BB * TT * DD + (size_t)bt] = 1.0f;                 // out_mask
    }
}

extern "C" void kernel_launch(void* const* d_in, const int* in_sizes, int n_in,
                              void* d_out, int out_size, void* d_ws, size_t ws_size,
                              hipStream_t stream) {
    const float* x    = (const float*)d_in[0];
    const void*  mask = d_in[1];
    // d_in[2] = finallength (always 1024, hard-coded as TT)
    float* out = (float*)d_out;

    changelen_fused<<<(BB * TT) / 4, 256, 0, stream>>>(x, mask, out);
}

// Round 3
// 81.171 us; speedup vs baseline: 1.1493x; 1.0175x over previous
//
#include <hip/hip_runtime.h>
#include <hip/hip_bf16.h>
#include <math.h>

// Problem constants (from reference file: B=8, L_IN=4096, D=256, T_OUT=1024)
#define BB   8
#define LL   4096
#define DD   256
#define TT   1024
#define EPSV 1e-12f

// ---------------------------------------------------------------------------
// Single fused kernel. One WAVE per (b,t) output bin; 4 bins per 256-thread
// block. Lane handles 4 channels via float4 (row = 64 lanes x 16 B = 1 KB
// contiguous transaction).
//
// Lb recovered per-wave by 64-ary search on the prefix mask (2 dependent
// L2-hit loads + ballot/popcount).
//
// Inner accumulation is a STRAIGHT-LINE 5-row unroll: with step = Lb/1024 in
// [2,4], the support [floor(start), ceil(end)) spans at most 5 rows. Rows
// beyond the support get w=0 / A-mask=0; row index clamped to LL-1 so
// speculative loads stay in-buffer (their values are multiplied by 0).
// Speculative rows are the next bin's rows -> L2 hits, no HBM overfetch.
// All weight math exact in f32 (t*Lb < 2^22); Wsum == step exactly.
// ---------------------------------------------------------------------------
__global__ __launch_bounds__(256) void changelen_fused(const float* __restrict__ x,
                                                       const void* __restrict__ mask,
                                                       float* __restrict__ out) {
    const int wave = threadIdx.x >> 6;
    const int lane = threadIdx.x & 63;
    const int bt   = (blockIdx.x << 2) + wave;   // 0 .. B*T-1
    const int b    = bt >> 10;                   // / TT
    const int t    = bt & (TT - 1);              // % TT

    // ---- 64-ary prefix-mask search for Lb ----
    const int* mi32 = (const int*)mask;
    const unsigned char* mu8 = (const unsigned char*)mask;
    const bool is_i32 = (mi32[0] == 1);          // layout probe (mask[0][0] is true)

    bool p1;
    if (is_i32) p1 = (mi32[(size_t)b * LL + lane * 64 + 63] != 0);
    else        p1 = (mu8 [(size_t)b * LL + lane * 64 + 63] != 0);
    const int n1 = __popcll(__ballot(p1));       // floor(Lb/64)
    int Lbi;
    if (n1 == 64) {
        Lbi = LL;                                // all-true row; avoid OOB probe
    } else {
        const int base = n1 << 6;
        bool p2;
        if (is_i32) p2 = (mi32[(size_t)b * LL + base + lane] != 0);
        else        p2 = (mu8 [(size_t)b * LL + base + lane] != 0);
        Lbi = base + __popcll(__ballot(p2));
    }

    // ---- bin geometry (exact in f32) ----
    const float Lb    = (float)Lbi;
    const float step  = Lb * (1.0f / (float)TT);
    const float start = (float)t * step;
    const float end   = start + step;
    const float s_f   = floorf(start);
    const float e_f   = ceilf(end);
    const int   s     = (int)s_f;
    const int   e     = (int)e_f;                // e <= Lbi <= LL
    const float inv_cnt = 1.0f / fmaxf(e_f - s_f, 1.0f);

    // ---- 5 unconditional row loads (back-to-back, max MLP) ----
    float4 v[5];
    const float* xb = x + (size_t)b * LL * DD;
    #pragma unroll
    for (int k = 0; k < 5; ++k) {
        int row = s + k;
        row = row < (LL - 1) ? row : (LL - 1);   // stay in-buffer; w=0 there
        v[k] = ((const float4*)(xb + (size_t)row * DD))[lane];
    }

    // ---- straight-line accumulate ----
    float4 sumA = {0.f, 0.f, 0.f, 0.f};
    float4 sw   = {0.f, 0.f, 0.f, 0.f};
    float4 sw2  = {0.f, 0.f, 0.f, 0.f};
    #pragma unroll
    for (int k = 0; k < 5; ++k) {
        const float fi = (float)(s + k);
        float w = fminf(fi + 1.0f, end) - fmaxf(fi, start);
        w = fmaxf(w, 0.0f);                              // 0 for rows >= e
        const float am = (s + k < e) ? inv_cnt : 0.0f;   // A-weight (1/cnt folded)
        sumA.x = fmaf(am, v[k].x, sumA.x); sumA.y = fmaf(am, v[k].y, sumA.y);
        sumA.z = fmaf(am, v[k].z, sumA.z); sumA.w = fmaf(am, v[k].w, sumA.w);
        sw.x = fmaf(w, v[k].x, sw.x); sw.y = fmaf(w, v[k].y, sw.y);
        sw.z = fmaf(w, v[k].z, sw.z); sw.w = fmaf(w, v[k].w, sw.w);
        sw2.x = fmaf(w, v[k].x * v[k].x, sw2.x); sw2.y = fmaf(w, v[k].y * v[k].y, sw2.y);
        sw2.z = fmaf(w, v[k].z * v[k].z, sw2.z); sw2.w = fmaf(w, v[k].w * v[k].w, sw2.w);
    }

    // ---- epilogue: std; vector stores ----
    float4 stdv;
    {
        const float inv_s = 1.0f / step;
        const float mx = sw.x * inv_s, my = sw.y * inv_s, mz = sw.z * inv_s, mw = sw.w * inv_s;
        const float qx = sw2.x * inv_s, qy = sw2.y * inv_s, qz = sw2.z * inv_s, qw = sw2.w * inv_s;
        stdv.x = sqrtf(fmaxf(qx - mx * mx, EPSV));
        stdv.y = sqrtf(fmaxf(qy - my * my, EPSV));
        stdv.z = sqrtf(fmaxf(qz - mz * mz, EPSV));
        stdv.w = sqrtf(fmaxf(qw - mw * mw, EPSV));
    }

    float4* out4 = (float4*)out;
    const size_t o_pool4 = (size_t)bt * (DD / 4) + (size_t)lane;       // padded_out
    // std_out starts after padded_out (B*T*D floats) + out_mask (B*T floats);
    // offset (2,105,344 floats) is 16B-aligned.
    const size_t std_base4 = ((size_t)BB * TT * DD + (size_t)BB * TT) / 4;
    out4[o_pool4] = sumA;
    out4[std_base4 + o_pool4] = stdv;
    if (lane == 0) {
        out[(size_t)BB * TT * DD + (size_t)bt] = 1.0f;                 // out_mask
    }
}

extern "C" void kernel_launch(void* const* d_in, const int* in_sizes, int n_in,
                              void* d_out, int out_size, void* d_ws, size_t ws_size,
                              hipStream_t stream) {
    const float* x    = (const float*)d_in[0];
    const void*  mask = d_in[1];
    // d_in[2] = finallength (always 1024, hard-coded as TT)
    float* out = (float*)d_out;

    changelen_fused<<<(BB * TT) / 4, 256, 0, stream>>>(x, mask, out);
}